// Round 7
// baseline (247.383 us; speedup 1.0000x reference)
//
#include <hip/hip_runtime.h>
#include <math.h>

#define NBINS 15

// DPP quad_perm helpers (pure VALU cross-lane within groups of 4 lanes).
template<int CTRL>
__device__ __forceinline__ float dpp_f(float x) {
    return __int_as_float(__builtin_amdgcn_update_dpp(
        0, __float_as_int(x), CTRL, 0xF, 0xF, true));
}
template<int CTRL>
__device__ __forceinline__ int dpp_i(int x) {
    return __builtin_amdgcn_update_dpp(0, x, CTRL, 0xF, 0xF, true);
}
#define QP_XOR1 0xB1   // quad_perm {1,0,3,2}
#define QP_XOR2 0x4E   // quad_perm {2,3,0,1}

// 4 lanes per row (R6 structure, 155.6us) + VGPR-neutral software pipeline:
// consume c_k, then immediately issue next chunk's n_k into the freed slot.
// Next-chunk loads stay in flight across the DPP-combine/atomic/latch phase,
// raising outstanding-bytes duty cycle. Finalize fused via last-block ticket.
__global__ __launch_bounds__(256) void ce_rows100(const float* __restrict__ logits,
                                                  const int* __restrict__ labels,
                                                  float* __restrict__ gbins,
                                                  unsigned int* __restrict__ ticket,
                                                  float* __restrict__ out,
                                                  int N, float inv_n,
                                                  unsigned int nblocks) {
    __shared__ float sb[NBINS * 3];
    __shared__ int slast;
    if (threadIdx.x < NBINS * 3) sb[threadIdx.x] = 0.f;
    if (threadIdx.x == 0) slast = 0;
    __syncthreads();

    const int lane = threadIdx.x & 63;
    const int q = lane & 3;        // lane within quad
    const int rq = lane >> 2;      // row within 16-row chunk
    const int gw = (blockIdx.x * blockDim.x + threadIdx.x) >> 6;
    const int nw = (gridDim.x * blockDim.x) >> 6;
    const int nchunks = (N + 15) >> 4;

    float4 c0, c1, c2, c3, c4, c5;
    float ct = 0.f;
    int clab = 0;
    int chunk = gw;
    {   // prologue load
        const int row = chunk * 16 + rq;
        if (chunk < nchunks && row < N) {
            const float* rpf = logits + (size_t)row * 100;
            const float4* rp = reinterpret_cast<const float4*>(rpf);
            clab = labels[row];
            c0 = rp[q];      c1 = rp[4 + q];  c2 = rp[8 + q];
            c3 = rp[12 + q]; c4 = rp[16 + q]; c5 = rp[20 + q];
            ct = rpf[96 + q];
        }
    }

    while (chunk < nchunks) {
        const int row = chunk * 16 + rq;
        const bool rv = row < N;
        const int nchunk_i = chunk + nw;
        const int nrow = nchunk_i * 16 + rq;
        const bool nv = (nchunk_i < nchunks) && (nrow < N);
        const float* nrpf = logits + (size_t)nrow * 100;
        const float4* nrp = reinterpret_cast<const float4*>(nrpf);

        float4 n0, n1, n2, n3, n4, n5;
        float nt = 0.f;
        int nlab = 0;
        const int lab = clab;

        float m = -INFINITY, s = 0.f;
        int arg = 0;
        auto cons = [&](const float4& v, int bi) {
            { float x = v.x; if (x > m) { s *= __expf(m - x); m = x; arg = bi;     } s += __expf(x - m); }
            { float x = v.y; if (x > m) { s *= __expf(m - x); m = x; arg = bi + 1; } s += __expf(x - m); }
            { float x = v.z; if (x > m) { s *= __expf(m - x); m = x; arg = bi + 2; } s += __expf(x - m); }
            { float x = v.w; if (x > m) { s *= __expf(m - x); m = x; arg = bi + 3; } s += __expf(x - m); }
        };

        if (rv & nv) {         // hot path: interleaved consume / prefetch
            nlab = labels[nrow];
            cons(c0, 4 * q);       n0 = nrp[q];
            cons(c1, 16 + 4 * q);  n1 = nrp[4 + q];
            cons(c2, 32 + 4 * q);  n2 = nrp[8 + q];
            cons(c3, 48 + 4 * q);  n3 = nrp[12 + q];
            cons(c4, 64 + 4 * q);  n4 = nrp[16 + q];
            cons(c5, 80 + 4 * q);  n5 = nrp[20 + q];
            { float x = ct; if (x > m) { s *= __expf(m - x); m = x; arg = 96 + q; } s += __expf(x - m); }
            nt = nrpf[96 + q];
        } else {               // boundary path (first/last sweeps, row tails)
            if (rv) {
                cons(c0, 4 * q);      cons(c1, 16 + 4 * q); cons(c2, 32 + 4 * q);
                cons(c3, 48 + 4 * q); cons(c4, 64 + 4 * q); cons(c5, 80 + 4 * q);
                { float x = ct; if (x > m) { s *= __expf(m - x); m = x; arg = 96 + q; } s += __expf(x - m); }
            }
            if (nv) {
                nlab = labels[nrow];
                n0 = nrp[q];      n1 = nrp[4 + q];  n2 = nrp[8 + q];
                n3 = nrp[12 + q]; n4 = nrp[16 + q]; n5 = nrp[20 + q];
                nt = nrpf[96 + q];
            }
        }

        if (rv) {
            // quad argmax butterfly (first-occurrence tie-break)
            const float ml = m;
            float M = m; int A = arg;
            {
                float t = dpp_f<QP_XOR1>(M); int ti = dpp_i<QP_XOR1>(A);
                if (t > M || (t == M && ti < A)) { M = t; A = ti; }
                t = dpp_f<QP_XOR2>(M); ti = dpp_i<QP_XOR2>(A);
                if (t > M || (t == M && ti < A)) { M = t; A = ti; }
            }
            float sc = s * __expf(ml - M);
            sc += dpp_f<QP_XOR1>(sc);
            sc += dpp_f<QP_XOR2>(sc);

            if (q == 0) {
                const float conf = 1.0f / sc;      // max softmax prob
                int b = (int)ceilf(conf * (float)NBINS) - 1;
                b = min(max(b, 0), NBINS - 1);
                atomicAdd(&sb[b * 3 + 0], 1.0f);
                atomicAdd(&sb[b * 3 + 1], conf);
                if (A == lab) atomicAdd(&sb[b * 3 + 2], 1.0f);
            }
        }

        c0 = n0; c1 = n1; c2 = n2; c3 = n3; c4 = n4; c5 = n5;
        ct = nt; clab = nlab;
        chunk = nchunk_i;
    }

    __syncthreads();
    if (threadIdx.x < NBINS * 3) {
        float v = sb[threadIdx.x];
        if (v != 0.f) atomicAdd(&gbins[threadIdx.x], v);
    }
    __syncthreads();
    if (threadIdx.x == 0) {
        __threadfence();
        unsigned int t = atomicAdd(ticket, 1u);
        if (t == nblocks - 1) slast = 1;
    }
    __syncthreads();
    if (slast && threadIdx.x < 64) {
        __threadfence();
        int t = threadIdx.x;
        float gap = 0.f, w = 0.f;
        bool ne = false;
        if (t < NBINS) {
            // device-scope coherent reads (atomic RMW with 0)
            float c  = atomicAdd(&gbins[t * 3 + 0], 0.f);
            float sc = atomicAdd(&gbins[t * 3 + 1], 0.f);
            float sa = atomicAdd(&gbins[t * 3 + 2], 0.f);
            if (c > 0.f) { ne = true; gap = fabsf(sc / c - sa / c); w = c; }
        }
        float ece = ne ? gap * w * inv_n : 0.f;
        float mce = ne ? gap : -INFINITY;
        #pragma unroll
        for (int off = 1; off < 64; off <<= 1) {
            ece += __shfl_xor(ece, off);
            mce = fmaxf(mce, __shfl_xor(mce, off));
        }
        if (t == 0) {
            out[0] = ece;
            out[1] = (mce == -INFINITY) ? 1.0f : mce;
        }
    }
}

// Generic fallback for C != 100 (scalar per-thread, correct for any C).
__global__ __launch_bounds__(256) void ce_rows_generic(const float* __restrict__ logits,
                                                       const int* __restrict__ labels,
                                                       float* __restrict__ gbins,
                                                       int N, int C) {
    __shared__ float sb[NBINS * 3];
    if (threadIdx.x < NBINS * 3) sb[threadIdx.x] = 0.f;
    __syncthreads();

    const int r = blockIdx.x * blockDim.x + threadIdx.x;
    if (r < N) {
        const float* rp = logits + (size_t)r * (size_t)C;
        float m = -INFINITY, s = 0.f;
        int arg = 0;
        for (int k = 0; k < C; ++k) {
            float x = rp[k];
            if (x > m) { s *= __expf(m - x); m = x; arg = k; }
            s += __expf(x - m);
        }
        float conf = 1.0f / s;
        int b = (int)ceilf(conf * (float)NBINS) - 1;
        b = min(max(b, 0), NBINS - 1);
        atomicAdd(&sb[b * 3 + 0], 1.0f);
        atomicAdd(&sb[b * 3 + 1], conf);
        if (arg == labels[r]) atomicAdd(&sb[b * 3 + 2], 1.0f);
    }
    __syncthreads();
    if (threadIdx.x < NBINS * 3) {
        float v = sb[threadIdx.x];
        if (v != 0.f) atomicAdd(&gbins[threadIdx.x], v);
    }
}

__global__ void ce_final(const float* __restrict__ gbins, float* __restrict__ out,
                         float inv_n) {
    int t = threadIdx.x;
    float gap = 0.f, w = 0.f;
    bool ne = false;
    if (t < NBINS) {
        float c = gbins[t * 3 + 0];
        float sc = gbins[t * 3 + 1];
        float sa = gbins[t * 3 + 2];
        if (c > 0.f) { ne = true; gap = fabsf(sc / c - sa / c); w = c; }
    }
    float ece = ne ? gap * w * inv_n : 0.f;
    float mce = ne ? gap : -INFINITY;
    #pragma unroll
    for (int off = 1; off < 64; off <<= 1) {
        ece += __shfl_xor(ece, off);
        mce = fmaxf(mce, __shfl_xor(mce, off));
    }
    if (t == 0) {
        out[0] = ece;
        out[1] = (mce == -INFINITY) ? 1.0f : mce;
    }
}

extern "C" void kernel_launch(void* const* d_in, const int* in_sizes, int n_in,
                              void* d_out, int out_size, void* d_ws, size_t ws_size,
                              hipStream_t stream) {
    const float* logits = (const float*)d_in[0];
    const int* labels = (const int*)d_in[1];
    int N = in_sizes[1];
    int C = in_sizes[0] / in_sizes[1];   // 100

    float* gbins = (float*)d_ws;
    unsigned int* ticket = (unsigned int*)(gbins + NBINS * 3);

    if (C == 100) {
        (void)hipMemsetAsync(gbins, 0, (NBINS * 3 + 1) * sizeof(float), stream);
        const unsigned int nblocks = 2048;
        ce_rows100<<<nblocks, 256, 0, stream>>>(logits, labels, gbins, ticket,
                                                (float*)d_out, N, 1.0f / (float)N,
                                                nblocks);
    } else {
        (void)hipMemsetAsync(gbins, 0, NBINS * 3 * sizeof(float), stream);
        ce_rows_generic<<<(N + 255) / 256, 256, 0, stream>>>(logits, labels, gbins, N, C);
        ce_final<<<1, 64, 0, stream>>>(gbins, (float*)d_out, 1.0f / (float)N);
    }
}

// Round 9
// 190.891 us; speedup vs baseline: 1.2959x; 1.2959x over previous
//
#include <hip/hip_runtime.h>
#include <math.h>

#define NBINS 15

typedef float floatx4 __attribute__((ext_vector_type(4)));

// DPP quad_perm helpers (pure VALU cross-lane within groups of 4 lanes).
template<int CTRL>
__device__ __forceinline__ float dpp_f(float x) {
    return __int_as_float(__builtin_amdgcn_update_dpp(
        0, __float_as_int(x), CTRL, 0xF, 0xF, true));
}
template<int CTRL>
__device__ __forceinline__ int dpp_i(int x) {
    return __builtin_amdgcn_update_dpp(0, x, CTRL, 0xF, 0xF, true);
}
#define QP_XOR1 0xB1   // quad_perm {1,0,3,2}
#define QP_XOR2 0x4E   // quad_perm {2,3,0,1}

// R6 structure (155.6us, best so far), single delta: nontemporal loads on the
// 800MB read-once logits stream (nt bit -> no L2 retention churn). Loads go
// through clang ext_vector_type(4) since the builtin rejects HIP_vector_type.
// 4 lanes per row: lane q loads float4-quads {q,4+q,...,20+q} (one contiguous
// 64B segment per row per instruction), online softmax per lane, quad combine
// via 2 DPP steps, balanced tail (lane q handles element 96+q).
__global__ __launch_bounds__(256) void ce_rows100(const float* __restrict__ logits,
                                                  const int* __restrict__ labels,
                                                  float* __restrict__ gbins, int N) {
    __shared__ float sb[NBINS * 3];
    if (threadIdx.x < NBINS * 3) sb[threadIdx.x] = 0.f;
    __syncthreads();

    const int lane = threadIdx.x & 63;
    const int q = lane & 3;        // lane within quad
    const int rq = lane >> 2;      // row within 16-row chunk
    const int gw = (blockIdx.x * blockDim.x + threadIdx.x) >> 6;
    const int nw = (gridDim.x * blockDim.x) >> 6;
    const int nchunks = (N + 15) >> 4;

    for (int chunk = gw; chunk < nchunks; chunk += nw) {
        const int row = chunk * 16 + rq;
        if (row < N) {
            const float* rpf = logits + (size_t)row * 100;
            const floatx4* rp = reinterpret_cast<const floatx4*>(rpf);
            const int lab = labels[row];          // uniform per quad, early issue

            float m = -INFINITY, s = 0.f;
            int arg = 0;
            #pragma unroll
            for (int k = 0; k < 6; ++k) {
                const int qi = 4 * k + q;          // quad index in row, < 24
                floatx4 v = __builtin_nontemporal_load(rp + qi);
                const int bi = qi * 4;
                { float x = v.x; if (x > m) { s *= __expf(m - x); m = x; arg = bi;     } s += __expf(x - m); }
                { float x = v.y; if (x > m) { s *= __expf(m - x); m = x; arg = bi + 1; } s += __expf(x - m); }
                { float x = v.z; if (x > m) { s *= __expf(m - x); m = x; arg = bi + 2; } s += __expf(x - m); }
                { float x = v.w; if (x > m) { s *= __expf(m - x); m = x; arg = bi + 3; } s += __expf(x - m); }
            }
            // balanced tail: lane q handles element 96+q (all lanes active)
            {
                float x = __builtin_nontemporal_load(rpf + 96 + q);
                if (x > m) { s *= __expf(m - x); m = x; arg = 96 + q; }
                s += __expf(x - m);
            }

            // quad argmax butterfly (first-occurrence: equal max -> smaller index)
            const float ml = m;
            float M = m; int A = arg;
            {
                float t = dpp_f<QP_XOR1>(M); int ti = dpp_i<QP_XOR1>(A);
                if (t > M || (t == M && ti < A)) { M = t; A = ti; }
                t = dpp_f<QP_XOR2>(M); ti = dpp_i<QP_XOR2>(A);
                if (t > M || (t == M && ti < A)) { M = t; A = ti; }
            }
            // quad sum of s_l * exp(m_l - M)
            float sc = s * __expf(ml - M);
            sc += dpp_f<QP_XOR1>(sc);
            sc += dpp_f<QP_XOR2>(sc);

            if (q == 0) {
                const float conf = 1.0f / sc;      // max softmax prob
                int b = (int)ceilf(conf * (float)NBINS) - 1;
                b = min(max(b, 0), NBINS - 1);
                atomicAdd(&sb[b * 3 + 0], 1.0f);
                atomicAdd(&sb[b * 3 + 1], conf);
                if (A == lab) atomicAdd(&sb[b * 3 + 2], 1.0f);
            }
        }
    }

    __syncthreads();
    if (threadIdx.x < NBINS * 3) {
        float v = sb[threadIdx.x];
        if (v != 0.f) atomicAdd(&gbins[threadIdx.x], v);
    }
}

// Generic fallback for C != 100 (scalar per-thread, correct for any C).
__global__ __launch_bounds__(256) void ce_rows_generic(const float* __restrict__ logits,
                                                       const int* __restrict__ labels,
                                                       float* __restrict__ gbins,
                                                       int N, int C) {
    __shared__ float sb[NBINS * 3];
    if (threadIdx.x < NBINS * 3) sb[threadIdx.x] = 0.f;
    __syncthreads();

    const int r = blockIdx.x * blockDim.x + threadIdx.x;
    if (r < N) {
        const float* rp = logits + (size_t)r * (size_t)C;
        float m = -INFINITY, s = 0.f;
        int arg = 0;
        for (int k = 0; k < C; ++k) {
            float x = rp[k];
            if (x > m) { s *= __expf(m - x); m = x; arg = k; }
            s += __expf(x - m);
        }
        float conf = 1.0f / s;
        int b = (int)ceilf(conf * (float)NBINS) - 1;
        b = min(max(b, 0), NBINS - 1);
        atomicAdd(&sb[b * 3 + 0], 1.0f);
        atomicAdd(&sb[b * 3 + 1], conf);
        if (arg == labels[r]) atomicAdd(&sb[b * 3 + 2], 1.0f);
    }
    __syncthreads();
    if (threadIdx.x < NBINS * 3) {
        float v = sb[threadIdx.x];
        if (v != 0.f) atomicAdd(&gbins[threadIdx.x], v);
    }
}

__global__ void ce_final(const float* __restrict__ gbins, float* __restrict__ out,
                         float inv_n) {
    int t = threadIdx.x;
    float gap = 0.f, w = 0.f;
    bool ne = false;
    if (t < NBINS) {
        float c = gbins[t * 3 + 0];
        float sc = gbins[t * 3 + 1];
        float sa = gbins[t * 3 + 2];
        if (c > 0.f) { ne = true; gap = fabsf(sc / c - sa / c); w = c; }
    }
    float ece = ne ? gap * w * inv_n : 0.f;
    float mce = ne ? gap : -INFINITY;
    #pragma unroll
    for (int off = 1; off < 64; off <<= 1) {
        ece += __shfl_xor(ece, off);
        mce = fmaxf(mce, __shfl_xor(mce, off));
    }
    if (t == 0) {
        out[0] = ece;
        out[1] = (mce == -INFINITY) ? 1.0f : mce;
    }
}

extern "C" void kernel_launch(void* const* d_in, const int* in_sizes, int n_in,
                              void* d_out, int out_size, void* d_ws, size_t ws_size,
                              hipStream_t stream) {
    const float* logits = (const float*)d_in[0];
    const int* labels = (const int*)d_in[1];
    int N = in_sizes[1];
    int C = in_sizes[0] / in_sizes[1];   // 100

    float* gbins = (float*)d_ws;
    (void)hipMemsetAsync(gbins, 0, NBINS * 3 * sizeof(float), stream);

    if (C == 100) {
        ce_rows100<<<2048, 256, 0, stream>>>(logits, labels, gbins, N);
    } else {
        ce_rows_generic<<<(N + 255) / 256, 256, 0, stream>>>(logits, labels, gbins, N, C);
    }
    ce_final<<<1, 64, 0, stream>>>(gbins, (float*)d_out, 1.0f / (float)N);
}

// Round 10
// 161.280 us; speedup vs baseline: 1.5339x; 1.1836x over previous
//
#include <hip/hip_runtime.h>
#include <math.h>

#define NBINS 15

// DPP quad_perm helpers (pure VALU cross-lane within groups of 4 lanes).
template<int CTRL>
__device__ __forceinline__ float dpp_f(float x) {
    return __int_as_float(__builtin_amdgcn_update_dpp(
        0, __float_as_int(x), CTRL, 0xF, 0xF, true));
}
template<int CTRL>
__device__ __forceinline__ int dpp_i(int x) {
    return __builtin_amdgcn_update_dpp(0, x, CTRL, 0xF, 0xF, true);
}
#define QP_XOR1 0xB1   // quad_perm {1,0,3,2}
#define QP_XOR2 0x4E   // quad_perm {2,3,0,1}

// R6 compute (155.6us best) + LDS-staged loads: each wave copies its 16-row
// 6.4KB chunk with perfectly LINEAR global float4 loads (6x64 + masked 16,
// 1KB/instruction — same shape as the 6.6TB/s copy pattern), into a
// wave-private LDS region (no barriers; wave-internal lgkmcnt ordering).
// Compute then reads the quad pattern from LDS instead of scattered global.
__global__ __launch_bounds__(256) void ce_rows100(const float* __restrict__ logits,
                                                  const int* __restrict__ labels,
                                                  float* __restrict__ gbins, int N) {
    __shared__ float lds[4 * 1600];     // 4 waves x 16 rows x 100 floats = 25.6KB
    __shared__ float sb[NBINS * 3];
    if (threadIdx.x < NBINS * 3) sb[threadIdx.x] = 0.f;
    __syncthreads();

    const int lane = threadIdx.x & 63;
    const int wid = threadIdx.x >> 6;
    const int q = lane & 3;        // lane within quad
    const int rq = lane >> 2;      // row within 16-row chunk
    const int gw = (blockIdx.x * blockDim.x + threadIdx.x) >> 6;
    const int nw = (gridDim.x * blockDim.x) >> 6;
    const int nchunks = (N + 15) >> 4;

    float* const wl = lds + wid * 1600;          // this wave's staging region
    float4* const wlv = reinterpret_cast<float4*>(wl);

    for (int chunk = gw; chunk < nchunks; chunk += nw) {
        const int row = chunk * 16 + rq;
        const bool full = (chunk * 16 + 16) <= N;   // all 16 rows in range

        float m = -INFINITY, s = 0.f;
        int arg = 0;
        int lab = 0;

        if (full) {
            // ---- linear staging: 400 float4s, contiguous per instruction ----
            const float4* src = reinterpret_cast<const float4*>(logits) + (size_t)chunk * 400;
            #pragma unroll
            for (int j = 0; j < 6; ++j)
                wlv[j * 64 + lane] = src[j * 64 + lane];
            if (lane < 16)
                wlv[384 + lane] = src[384 + lane];

            lab = labels[row];

            // ---- R6 compute, reading from LDS (16B-aligned: 400=25*16) ----
            const float* rpf = wl + rq * 100;
            const float4* rp = reinterpret_cast<const float4*>(rpf);
            #pragma unroll
            for (int k = 0; k < 6; ++k) {
                const int qi = 4 * k + q;
                float4 v = rp[qi];
                const int bi = qi * 4;
                { float x = v.x; if (x > m) { s *= __expf(m - x); m = x; arg = bi;     } s += __expf(x - m); }
                { float x = v.y; if (x > m) { s *= __expf(m - x); m = x; arg = bi + 1; } s += __expf(x - m); }
                { float x = v.z; if (x > m) { s *= __expf(m - x); m = x; arg = bi + 2; } s += __expf(x - m); }
                { float x = v.w; if (x > m) { s *= __expf(m - x); m = x; arg = bi + 3; } s += __expf(x - m); }
            }
            { // balanced tail: lane q handles element 96+q
                float x = rpf[96 + q];
                if (x > m) { s *= __expf(m - x); m = x; arg = 96 + q; }
                s += __expf(x - m);
            }
        } else if (row < N) {
            // ---- rare partial chunk: R6 direct-global path ----
            const float* rpf = logits + (size_t)row * 100;
            const float4* rp = reinterpret_cast<const float4*>(rpf);
            lab = labels[row];
            #pragma unroll
            for (int k = 0; k < 6; ++k) {
                const int qi = 4 * k + q;
                float4 v = rp[qi];
                const int bi = qi * 4;
                { float x = v.x; if (x > m) { s *= __expf(m - x); m = x; arg = bi;     } s += __expf(x - m); }
                { float x = v.y; if (x > m) { s *= __expf(m - x); m = x; arg = bi + 1; } s += __expf(x - m); }
                { float x = v.z; if (x > m) { s *= __expf(m - x); m = x; arg = bi + 2; } s += __expf(x - m); }
                { float x = v.w; if (x > m) { s *= __expf(m - x); m = x; arg = bi + 3; } s += __expf(x - m); }
            }
            {
                float x = rpf[96 + q];
                if (x > m) { s *= __expf(m - x); m = x; arg = 96 + q; }
                s += __expf(x - m);
            }
        }

        if (full || row < N) {
            // quad argmax butterfly (first-occurrence: equal max -> smaller index)
            const float ml = m;
            float M = m; int A = arg;
            {
                float t = dpp_f<QP_XOR1>(M); int ti = dpp_i<QP_XOR1>(A);
                if (t > M || (t == M && ti < A)) { M = t; A = ti; }
                t = dpp_f<QP_XOR2>(M); ti = dpp_i<QP_XOR2>(A);
                if (t > M || (t == M && ti < A)) { M = t; A = ti; }
            }
            // quad sum of s_l * exp(m_l - M)
            float sc = s * __expf(ml - M);
            sc += dpp_f<QP_XOR1>(sc);
            sc += dpp_f<QP_XOR2>(sc);

            if (q == 0) {
                const float conf = 1.0f / sc;      // max softmax prob
                int b = (int)ceilf(conf * (float)NBINS) - 1;
                b = min(max(b, 0), NBINS - 1);
                atomicAdd(&sb[b * 3 + 0], 1.0f);
                atomicAdd(&sb[b * 3 + 1], conf);
                if (A == lab) atomicAdd(&sb[b * 3 + 2], 1.0f);
            }
        }
    }

    __syncthreads();
    if (threadIdx.x < NBINS * 3) {
        float v = sb[threadIdx.x];
        if (v != 0.f) atomicAdd(&gbins[threadIdx.x], v);
    }
}

// Generic fallback for C != 100 (scalar per-thread, correct for any C).
__global__ __launch_bounds__(256) void ce_rows_generic(const float* __restrict__ logits,
                                                       const int* __restrict__ labels,
                                                       float* __restrict__ gbins,
                                                       int N, int C) {
    __shared__ float sb[NBINS * 3];
    if (threadIdx.x < NBINS * 3) sb[threadIdx.x] = 0.f;
    __syncthreads();

    const int r = blockIdx.x * blockDim.x + threadIdx.x;
    if (r < N) {
        const float* rp = logits + (size_t)r * (size_t)C;
        float m = -INFINITY, s = 0.f;
        int arg = 0;
        for (int k = 0; k < C; ++k) {
            float x = rp[k];
            if (x > m) { s *= __expf(m - x); m = x; arg = k; }
            s += __expf(x - m);
        }
        float conf = 1.0f / s;
        int b = (int)ceilf(conf * (float)NBINS) - 1;
        b = min(max(b, 0), NBINS - 1);
        atomicAdd(&sb[b * 3 + 0], 1.0f);
        atomicAdd(&sb[b * 3 + 1], conf);
        if (arg == labels[r]) atomicAdd(&sb[b * 3 + 2], 1.0f);
    }
    __syncthreads();
    if (threadIdx.x < NBINS * 3) {
        float v = sb[threadIdx.x];
        if (v != 0.f) atomicAdd(&gbins[threadIdx.x], v);
    }
}

__global__ void ce_final(const float* __restrict__ gbins, float* __restrict__ out,
                         float inv_n) {
    int t = threadIdx.x;
    float gap = 0.f, w = 0.f;
    bool ne = false;
    if (t < NBINS) {
        float c = gbins[t * 3 + 0];
        float sc = gbins[t * 3 + 1];
        float sa = gbins[t * 3 + 2];
        if (c > 0.f) { ne = true; gap = fabsf(sc / c - sa / c); w = c; }
    }
    float ece = ne ? gap * w * inv_n : 0.f;
    float mce = ne ? gap : -INFINITY;
    #pragma unroll
    for (int off = 1; off < 64; off <<= 1) {
        ece += __shfl_xor(ece, off);
        mce = fmaxf(mce, __shfl_xor(mce, off));
    }
    if (t == 0) {
        out[0] = ece;
        out[1] = (mce == -INFINITY) ? 1.0f : mce;
    }
}

extern "C" void kernel_launch(void* const* d_in, const int* in_sizes, int n_in,
                              void* d_out, int out_size, void* d_ws, size_t ws_size,
                              hipStream_t stream) {
    const float* logits = (const float*)d_in[0];
    const int* labels = (const int*)d_in[1];
    int N = in_sizes[1];
    int C = in_sizes[0] / in_sizes[1];   // 100

    float* gbins = (float*)d_ws;
    (void)hipMemsetAsync(gbins, 0, NBINS * 3 * sizeof(float), stream);

    if (C == 100) {
        ce_rows100<<<2048, 256, 0, stream>>>(logits, labels, gbins, N);
    } else {
        ce_rows_generic<<<(N + 255) / 256, 256, 0, stream>>>(logits, labels, gbins, N, C);
    }
    ce_final<<<1, 64, 0, stream>>>(gbins, (float*)d_out, 1.0f / (float)N);
}